// Round 1
// baseline (259.435 us; speedup 1.0000x reference)
//
#include <hip/hip_runtime.h>
#include <hip/hip_bf16.h>

#define N_ROWS 8192
#define DIM 256
#define TEMP_INV 20.0f
// exp(x*20) = exp2(x * 20*log2(e))
#define EXP_SCALE 28.853900817779268f

typedef __attribute__((ext_vector_type(8))) short bf16x8;
typedef __attribute__((ext_vector_type(4))) float f32x4;

// ---------------------------------------------------------------------------
// 1) L2-normalize all 3 tensors, write bf16 rows to ws.
//    One wave (64 lanes) per row; lane holds 4 floats (float4 = 16B).
// ---------------------------------------------------------------------------
__global__ void __launch_bounds__(256) norm_kernel(
    const float* __restrict__ anc, const float* __restrict__ pos,
    const float* __restrict__ neg, __hip_bfloat16* __restrict__ out) {
  int wid = (blockIdx.x * 256 + threadIdx.x) >> 6;   // 0 .. 3*8192-1
  int lane = threadIdx.x & 63;
  const float* src = (wid < N_ROWS) ? anc : (wid < 2 * N_ROWS ? pos : neg);
  int r = wid & (N_ROWS - 1);
  float4 v = reinterpret_cast<const float4*>(src + (size_t)r * DIM)[lane];
  float ss = v.x * v.x + v.y * v.y + v.z * v.z + v.w * v.w;
#pragma unroll
  for (int m = 32; m; m >>= 1) ss += __shfl_xor(ss, m);
  float scale = 1.0f / fmaxf(sqrtf(ss), 1e-8f);
  union { __hip_bfloat16 h[4]; uint2 u; } pk;
  pk.h[0] = __float2bfloat16(v.x * scale);
  pk.h[1] = __float2bfloat16(v.y * scale);
  pk.h[2] = __float2bfloat16(v.z * scale);
  pk.h[3] = __float2bfloat16(v.w * scale);
  reinterpret_cast<uint2*>(out + (size_t)wid * DIM)[lane] = pk.u;
}

// ---------------------------------------------------------------------------
// 2) diag[i] = dot(a_n[i], p_n[i]) / TEMP  (bf16 inputs, fp32 accumulate)
//    Also zero-initializes rowsum (must be re-inited every call).
// ---------------------------------------------------------------------------
__global__ void __launch_bounds__(256) diag_kernel(
    const __hip_bfloat16* __restrict__ a_n, const __hip_bfloat16* __restrict__ p_n,
    float* __restrict__ diag, float* __restrict__ rowsum) {
  int wid = (blockIdx.x * 256 + threadIdx.x) >> 6;   // row 0..8191
  int lane = threadIdx.x & 63;
  uint2 ua = reinterpret_cast<const uint2*>(a_n + (size_t)wid * DIM)[lane];
  uint2 up = reinterpret_cast<const uint2*>(p_n + (size_t)wid * DIM)[lane];
  const __hip_bfloat16* ha = reinterpret_cast<const __hip_bfloat16*>(&ua);
  const __hip_bfloat16* hp = reinterpret_cast<const __hip_bfloat16*>(&up);
  float d = 0.f;
#pragma unroll
  for (int j = 0; j < 4; ++j)
    d += __bfloat162float(ha[j]) * __bfloat162float(hp[j]);
#pragma unroll
  for (int m = 32; m; m >>= 1) d += __shfl_xor(d, m);
  if (lane == 0) {
    diag[wid] = d * TEMP_INV;
    rowsum[wid] = 0.f;
  }
}

// ---------------------------------------------------------------------------
// 3) Fused GEMM + row-wise sum(exp(logit)).
//    Grid: 64 row-blocks x 16 col-chunks (1024 cols each).
//    Block: 4 waves; each wave owns 32 A-rows (A entirely in registers:
//    2 x 8 bf16x8 frags = 64 VGPR). Streams B 16 cols at a time:
//    8 B-frag global loads -> 16 MFMA (2 row-frags reuse each B-frag).
//    MFMA 16x16x32_bf16: A lane l holds A[l%16][(l/16)*8+e];
//    C lane l holds rows (l>>4)*4+q, col l&15  [verified layout].
// ---------------------------------------------------------------------------
__global__ void __launch_bounds__(256) fused_kernel(
    const __hip_bfloat16* __restrict__ a_n, const __hip_bfloat16* __restrict__ p_n,
    const __hip_bfloat16* __restrict__ n_n, float* __restrict__ rowsum) {
  const int lane = threadIdx.x & 63;
  const int w = threadIdx.x >> 6;
  const int rb = blockIdx.x >> 4;   // 0..63   (128 rows each)
  const int cc = blockIdx.x & 15;   // 0..15   (1024 cols each)
  const __hip_bfloat16* B = (cc < 8) ? (p_n + (size_t)cc * 1024 * DIM)
                                     : (n_n + (size_t)(cc - 8) * 1024 * DIM);
  const int row0 = rb * 128 + w * 32;
  const int ar = lane & 15;          // fragment row/col index
  const int ak = (lane >> 4) * 8;    // k sub-offset

  // A fragments for 32 rows x K=256, kept in registers.
  bf16x8 afrag[2][8];
#pragma unroll
  for (int rblk = 0; rblk < 2; ++rblk)
#pragma unroll
    for (int kk = 0; kk < 8; ++kk)
      afrag[rblk][kk] = *reinterpret_cast<const bf16x8*>(
          a_n + (size_t)(row0 + rblk * 16 + ar) * DIM + kk * 32 + ak);

  float psum0[4] = {0.f, 0.f, 0.f, 0.f};
  float psum1[4] = {0.f, 0.f, 0.f, 0.f};

  for (int ct = 0; ct < 64; ++ct) {  // 64 tiles of 16 columns
    const __hip_bfloat16* bbase = B + (size_t)(ct * 16 + ar) * DIM + ak;
    f32x4 acc0 = {0.f, 0.f, 0.f, 0.f};
    f32x4 acc1 = {0.f, 0.f, 0.f, 0.f};
#pragma unroll
    for (int kk = 0; kk < 8; ++kk) {
      bf16x8 bfrag = *reinterpret_cast<const bf16x8*>(bbase + kk * 32);
      acc0 = __builtin_amdgcn_mfma_f32_16x16x32_bf16(afrag[0][kk], bfrag, acc0, 0, 0, 0);
      acc1 = __builtin_amdgcn_mfma_f32_16x16x32_bf16(afrag[1][kk], bfrag, acc1, 0, 0, 0);
    }
    // logits bounded by +-20 -> direct exp, no max tracking needed.
#pragma unroll
    for (int q = 0; q < 4; ++q) {
      psum0[q] += exp2f(acc0[q] * EXP_SCALE);
      psum1[q] += exp2f(acc1[q] * EXP_SCALE);
    }
  }

  // Reduce the 16 column-lanes (same lane>>4 group) and accumulate per row.
#pragma unroll
  for (int rblk = 0; rblk < 2; ++rblk) {
#pragma unroll
    for (int q = 0; q < 4; ++q) {
      float s = (rblk == 0) ? psum0[q] : psum1[q];
      s += __shfl_xor(s, 1);
      s += __shfl_xor(s, 2);
      s += __shfl_xor(s, 4);
      s += __shfl_xor(s, 8);
      if ((lane & 15) == 0)
        atomicAdd(rowsum + row0 + rblk * 16 + (lane >> 4) * 4 + q, s);
    }
  }
}

// ---------------------------------------------------------------------------
// 4) loss = mean_i( log(rowsum[i]) - diag[i] )
// ---------------------------------------------------------------------------
__global__ void __launch_bounds__(256) loss_kernel(
    const float* __restrict__ rowsum, const float* __restrict__ diag,
    float* __restrict__ out) {
  __shared__ float sh[4];
  float acc = 0.f;
  for (int i = threadIdx.x; i < N_ROWS; i += 256)
    acc += logf(rowsum[i]) - diag[i];
#pragma unroll
  for (int m = 32; m; m >>= 1) acc += __shfl_xor(acc, m);
  if ((threadIdx.x & 63) == 0) sh[threadIdx.x >> 6] = acc;
  __syncthreads();
  if (threadIdx.x == 0) out[0] = (sh[0] + sh[1] + sh[2] + sh[3]) / (float)N_ROWS;
}

// ---------------------------------------------------------------------------
extern "C" void kernel_launch(void* const* d_in, const int* in_sizes, int n_in,
                              void* d_out, int out_size, void* d_ws, size_t ws_size,
                              hipStream_t stream) {
  const float* anc = (const float*)d_in[0];
  const float* pos = (const float*)d_in[1];
  const float* neg = (const float*)d_in[2];
  char* ws = (char*)d_ws;
  __hip_bfloat16* a_n = (__hip_bfloat16*)ws;                 // [8192][256] bf16
  __hip_bfloat16* p_n = a_n + (size_t)N_ROWS * DIM;
  __hip_bfloat16* n_n = p_n + (size_t)N_ROWS * DIM;
  float* diag = (float*)(ws + (size_t)3 * N_ROWS * DIM * 2); // 8192 f32
  float* rowsum = diag + N_ROWS;                             // 8192 f32
  float* out = (float*)d_out;

  norm_kernel<<<3 * N_ROWS / 4, 256, 0, stream>>>(anc, pos, neg, a_n);
  diag_kernel<<<N_ROWS / 4, 256, 0, stream>>>(a_n, p_n, diag, rowsum);
  fused_kernel<<<64 * 16, 256, 0, stream>>>(a_n, p_n, n_n, rowsum);
  loss_kernel<<<1, 256, 0, stream>>>(rowsum, diag, out);
}